// Round 1
// baseline (1009.020 us; speedup 1.0000x reference)
//
#include <hip/hip_runtime.h>
#include <math.h>

#define N_NODES 10000
#define N_EDGES 160000
#define N_GRAPH 512

#define NEG_INF (-1e30f)

// ======================= CSR build =======================
__global__ void k_count_edges(const int* __restrict__ dst, int* __restrict__ deg) {
  int e = blockIdx.x * 256 + threadIdx.x;
  if (e < N_EDGES) atomicAdd(&deg[dst[e]], 1);
}

__global__ void k_count_nodes(const int* __restrict__ batch, int* __restrict__ gcnt) {
  int i = blockIdx.x * 256 + threadIdx.x;
  if (i < N_NODES) atomicAdd(&gcnt[batch[i]], 1);
}

// single-block exclusive scan; out[n] = total
__global__ void k_scan(const int* __restrict__ in, int* __restrict__ out, int n) {
  __shared__ int buf[1024];
  __shared__ int carry_s;
  if (threadIdx.x == 0) carry_s = 0;
  __syncthreads();
  for (int base = 0; base < n; base += 1024) {
    int i = base + (int)threadIdx.x;
    int v = (i < n) ? in[i] : 0;
    buf[threadIdx.x] = v;
    __syncthreads();
    for (int off = 1; off < 1024; off <<= 1) {
      int t = (threadIdx.x >= (unsigned)off) ? buf[threadIdx.x - off] : 0;
      __syncthreads();
      buf[threadIdx.x] += t;
      __syncthreads();
    }
    int carry = carry_s;
    if (i < n) out[i] = carry + buf[threadIdx.x] - v;
    __syncthreads();
    if (threadIdx.x == 0) carry_s = carry + buf[1023];
    __syncthreads();
  }
  if (threadIdx.x == 0) out[n] = carry_s;
}

__global__ void k_fill(const int* __restrict__ src, const int* __restrict__ dst,
                       const int* __restrict__ rowoff, int* __restrict__ cursor,
                       int* __restrict__ csr) {
  int e = blockIdx.x * 256 + threadIdx.x;
  if (e < N_EDGES) {
    int d = dst[e];
    int p = atomicAdd(&cursor[d], 1);
    csr[rowoff[d] + p] = src[e];
  }
}

// deterministic order within each segment (atomic fill order varies run-to-run)
__global__ void k_sortseg(const int* __restrict__ rowoff, int* __restrict__ vals) {
  int i = blockIdx.x * 256 + threadIdx.x;
  if (i >= N_NODES) return;
  int a = rowoff[i], b = rowoff[i + 1];
  for (int p = a + 1; p < b; ++p) {
    int v = vals[p];
    int q = p - 1;
    while (q >= a && vals[q] > v) { vals[q + 1] = vals[q]; --q; }
    vals[q + 1] = v;
  }
}

// ======================= GEMM (fp32, 64x64x16 tile) =======================
// C[N,M] = A[N,K] @ W[K,M]; EPI=1: bias+BN+ReLU fused.
template <int EPI>
__global__ __launch_bounds__(256) void k_gemm(
    const float* __restrict__ A, const float* __restrict__ W,
    float* __restrict__ C, int N, int K, int M,
    const float* __restrict__ bias, const float* __restrict__ bn) {
  __shared__ float As[64][17];
  __shared__ float Ws[16][64];
  const int tx = threadIdx.x & 15;
  const int ty = threadIdx.x >> 4;
  const int m0 = blockIdx.y * 64;
  const int n0 = blockIdx.x * 64;
  float acc[4][4];
#pragma unroll
  for (int i = 0; i < 4; ++i)
#pragma unroll
    for (int j = 0; j < 4; ++j) acc[i][j] = 0.f;

  for (int kb = 0; kb < K; kb += 16) {
    // load A tile: 64 rows x 16 cols
#pragma unroll
    for (int p = 0; p < 4; ++p) {
      int mr = (int)(threadIdx.x >> 4) + p * 16;
      int kc = threadIdx.x & 15;
      int gm = m0 + mr;
      As[mr][kc] = (gm < N) ? A[(size_t)gm * K + kb + kc] : 0.f;
    }
    // load W tile: 16 rows x 64 cols
#pragma unroll
    for (int p = 0; p < 4; ++p) {
      int kr = (int)(threadIdx.x >> 6) + p * 4;
      int nc = threadIdx.x & 63;
      Ws[kr][nc] = W[(size_t)(kb + kr) * M + n0 + nc];
    }
    __syncthreads();
#pragma unroll
    for (int kk = 0; kk < 16; ++kk) {
      float a0 = As[ty * 4 + 0][kk];
      float a1 = As[ty * 4 + 1][kk];
      float a2 = As[ty * 4 + 2][kk];
      float a3 = As[ty * 4 + 3][kk];
      const float4 b4 = *(const float4*)&Ws[kk][tx * 4];
      acc[0][0] += a0 * b4.x; acc[0][1] += a0 * b4.y; acc[0][2] += a0 * b4.z; acc[0][3] += a0 * b4.w;
      acc[1][0] += a1 * b4.x; acc[1][1] += a1 * b4.y; acc[1][2] += a1 * b4.z; acc[1][3] += a1 * b4.w;
      acc[2][0] += a2 * b4.x; acc[2][1] += a2 * b4.y; acc[2][2] += a2 * b4.z; acc[2][3] += a2 * b4.w;
      acc[3][0] += a3 * b4.x; acc[3][1] += a3 * b4.y; acc[3][2] += a3 * b4.z; acc[3][3] += a3 * b4.w;
    }
    __syncthreads();
  }

  const int gn0 = n0 + tx * 4;
#pragma unroll
  for (int i = 0; i < 4; ++i) {
    int gm = m0 + ty * 4 + i;
    if (gm < N) {
      alignas(16) float rr[4];
#pragma unroll
      for (int j = 0; j < 4; ++j) {
        float v = acc[i][j];
        if (EPI == 1) {
          int gn = gn0 + j;
          v += bias[gn];
          float g = bn[gn], b = bn[M + gn], mu = bn[2 * M + gn], var = bn[3 * M + gn];
          v = (v - mu) * (g * rsqrtf(var + 1e-5f)) + b;
          v = v > 0.f ? v : 0.f;
        }
        rr[j] = v;
      }
      *(float4*)&C[(size_t)gm * M + gn0] = *(const float4*)rr;
    }
  }
}

// ======================= attention scores =======================
// aS[n,h] = dot(h[n,h,:], att_src[h,:]); aD likewise. one wave per (node,head).
template <int HEADS>
__global__ __launch_bounds__(64) void k_att(const float* __restrict__ h,
                                            const float* __restrict__ att_s,
                                            const float* __restrict__ att_d,
                                            float* __restrict__ aS,
                                            float* __restrict__ aD) {
  const int b = blockIdx.x;  // N_NODES*HEADS
  const int node = b / HEADS, hd = b % HEADS;
  const int lane = threadIdx.x;
  const float* row = h + (size_t)node * HEADS * 256 + hd * 256;
  float ss = 0.f, sd = 0.f;
#pragma unroll
  for (int j = 0; j < 4; ++j) {
    float x = row[lane + 64 * j];
    ss += x * att_s[hd * 256 + lane + 64 * j];
    sd += x * att_d[hd * 256 + lane + 64 * j];
  }
#pragma unroll
  for (int off = 32; off; off >>= 1) {
    ss += __shfl_xor(ss, off);
    sd += __shfl_xor(sd, off);
  }
  if (lane == 0) {
    aS[node * HEADS + hd] = ss;
    aD[node * HEADS + hd] = sd;
  }
}

// ======================= fused GAT aggregation =======================
// per destination node: softmax over incoming edges + weighted gather-sum,
// then +bias, BN(eval), ELU. One block (256 thr) per node.
template <int HEADS, int CHN>
__global__ __launch_bounds__(256) void k_gat_agg(
    const float* __restrict__ hpre, const float* __restrict__ aS,
    const float* __restrict__ aD, const int* __restrict__ rowoff,
    const int* __restrict__ csr, const float* __restrict__ bias,
    const float* __restrict__ bn, float* __restrict__ out) {
  constexpr int HC = HEADS * CHN;   // 1024 or 256
  constexpr int CPT = HC / 256;     // 4 or 1
  const int node = blockIdx.x;
  const int tid = threadIdx.x;
  const int lane = tid & 63, wave = tid >> 6;
  const int r0 = rowoff[node], r1 = rowoff[node + 1];
  const int deg = r1 - r0;

  __shared__ float s_m[HEADS], s_d[HEADS];
  __shared__ float s_alpha[HEADS * 64];
  __shared__ int s_src[64];

  // phase 1: per-head max and denom (wave w handles head w)
  if (wave < HEADS) {
    const float adn = aD[node * HEADS + wave];
    float mx = NEG_INF;
    for (int i = lane; i < deg; i += 64) {
      int s = csr[r0 + i];
      float l = aS[s * HEADS + wave] + adn;
      l = l > 0.f ? l : 0.2f * l;
      mx = fmaxf(mx, l);
    }
#pragma unroll
    for (int off = 32; off; off >>= 1) mx = fmaxf(mx, __shfl_xor(mx, off));
    float sum = 0.f;
    for (int i = lane; i < deg; i += 64) {
      int s = csr[r0 + i];
      float l = aS[s * HEADS + wave] + adn;
      l = l > 0.f ? l : 0.2f * l;
      sum += __expf(l - mx);
    }
#pragma unroll
    for (int off = 32; off; off >>= 1) sum += __shfl_xor(sum, off);
    if (lane == 0) {
      s_m[wave] = mx;
      s_d[wave] = 1.f / (sum + 1e-16f);
    }
  }
  __syncthreads();

  // phase 2: chunked alpha + weighted accumulate
  float acc[CPT];
#pragma unroll
  for (int j = 0; j < CPT; ++j) acc[j] = 0.f;
  const int c0 = tid * CPT;
  const int head = c0 / CHN;

  for (int e0 = 0; e0 < deg; e0 += 64) {
    const int cnt = min(64, deg - e0);
    const int eL = tid & 63, hh = tid >> 6;
    if (hh < HEADS && eL < cnt) {
      int s = csr[r0 + e0 + eL];
      if (hh == 0) s_src[eL] = s;
      float l = aS[s * HEADS + hh] + aD[node * HEADS + hh];
      l = l > 0.f ? l : 0.2f * l;
      s_alpha[hh * 64 + eL] = __expf(l - s_m[hh]) * s_d[hh];
    }
    __syncthreads();
    for (int e = 0; e < cnt; ++e) {
      const int s = s_src[e];
      const float al = s_alpha[head * 64 + e];
      if constexpr (CPT == 4) {
        const float4 v = *(const float4*)(hpre + (size_t)s * HC + c0);
        acc[0] += al * v.x;
        acc[1] += al * v.y;
        acc[2] += al * v.z;
        acc[3] += al * v.w;
      } else {
        acc[0] += al * hpre[(size_t)s * HC + c0];
      }
    }
    __syncthreads();
  }

  // epilogue: +bias, BN(eval), ELU
  if constexpr (CPT == 4) {
    alignas(16) float rr[4];
#pragma unroll
    for (int j = 0; j < 4; ++j) {
      int c = c0 + j;
      float v = acc[j] + bias[c];
      float g = bn[c], b = bn[HC + c], mu = bn[2 * HC + c], var = bn[3 * HC + c];
      v = (v - mu) * (g * rsqrtf(var + 1e-5f)) + b;
      v = v > 0.f ? v : (__expf(v) - 1.f);
      rr[j] = v;
    }
    *(float4*)&out[(size_t)node * HC + c0] = *(const float4*)rr;
  } else {
    int c = c0;
    float v = acc[0] + bias[c];
    float g = bn[c], b = bn[HC + c], mu = bn[2 * HC + c], var = bn[3 * HC + c];
    v = (v - mu) * (g * rsqrtf(var + 1e-5f)) + b;
    v = v > 0.f ? v : (__expf(v) - 1.f);
    out[(size_t)node * HC + c] = v;
  }
}

// ======================= graph readout =======================
// z[g] = [mean | max | sum] over nodes of graph g. one block per graph, thread = channel.
__global__ __launch_bounds__(256) void k_pool(const float* __restrict__ h,
                                              const int* __restrict__ goff,
                                              float* __restrict__ z) {
  const int g = blockIdx.x;
  const int c = threadIdx.x;  // 256
  const int i0 = goff[g], i1 = goff[g + 1];
  float s = 0.f, mx = NEG_INF;
  for (int i = i0; i < i1; ++i) {
    float v = h[(size_t)i * 256 + c];
    s += v;
    mx = fmaxf(mx, v);
  }
  const float cnt = (float)(i1 - i0);
  z[(size_t)g * 768 + c] = s / cnt;
  z[(size_t)g * 768 + 256 + c] = mx;
  z[(size_t)g * 768 + 512 + c] = s;
}

// ======================= fc3 =======================
__global__ __launch_bounds__(64) void k_fc3(const float* __restrict__ z2,
                                            const float* __restrict__ w,
                                            const float* __restrict__ b,
                                            float* __restrict__ out) {
  const int g = blockIdx.x;
  const int lane = threadIdx.x;
  float s = 0.f;
#pragma unroll
  for (int j = 0; j < 4; ++j) {
    int c = lane + 64 * j;
    s += z2[(size_t)g * 256 + c] * w[c];
  }
#pragma unroll
  for (int off = 32; off; off >>= 1) s += __shfl_xor(s, off);
  if (lane == 0) out[g] = s + b[0];
}

// ======================= host launch =======================
extern "C" void kernel_launch(void* const* d_in, const int* in_sizes, int n_in,
                              void* d_out, int out_size, void* d_ws, size_t ws_size,
                              hipStream_t stream) {
  const float* x    = (const float*)d_in[0];
  const int* ei     = (const int*)d_in[1];
  const int* batch  = (const int*)d_in[2];
  const float* W1   = (const float*)d_in[3];
  const float* as1  = (const float*)d_in[4];
  const float* ad1  = (const float*)d_in[5];
  const float* b1   = (const float*)d_in[6];
  const float* bn1  = (const float*)d_in[7];
  const float* W2   = (const float*)d_in[8];
  const float* as2  = (const float*)d_in[9];
  const float* ad2  = (const float*)d_in[10];
  const float* b2   = (const float*)d_in[11];
  const float* bn2  = (const float*)d_in[12];
  const float* W3   = (const float*)d_in[13];
  const float* as3  = (const float*)d_in[14];
  const float* ad3  = (const float*)d_in[15];
  const float* b3   = (const float*)d_in[16];
  const float* bn3  = (const float*)d_in[17];
  const float* fc1w = (const float*)d_in[18];
  const float* fc1b = (const float*)d_in[19];
  const float* bnf1 = (const float*)d_in[20];
  const float* fc2w = (const float*)d_in[21];
  const float* fc2b = (const float*)d_in[22];
  const float* bnf2 = (const float*)d_in[23];
  const float* fc3w = (const float*)d_in[24];
  const float* fc3b = (const float*)d_in[25];
  float* out = (float*)d_out;

  const int* e_src = ei;
  const int* e_dst = ei + N_EDGES;

  // workspace carve-out
  char* w = (char*)d_ws;
  auto alloc = [&](size_t bytes) -> void* {
    void* p = (void*)w;
    w += (bytes + 255) & ~(size_t)255;
    return p;
  };
  float* hA   = (float*)alloc((size_t)N_NODES * 1024 * 4);
  float* hB   = (float*)alloc((size_t)N_NODES * 1024 * 4);
  float* aS   = (float*)alloc((size_t)N_NODES * 4 * 4);
  float* aD   = (float*)alloc((size_t)N_NODES * 4 * 4);
  int* deg    = (int*)alloc((size_t)(2 * N_NODES + N_GRAPH) * 4);  // deg|cursor|gcnt
  int* cursor = deg + N_NODES;
  int* gcnt   = deg + 2 * N_NODES;
  int* rowoff = (int*)alloc((size_t)(N_NODES + 1) * 4);
  int* goff   = (int*)alloc((size_t)(N_GRAPH + 1) * 4);
  int* csr    = (int*)alloc((size_t)N_EDGES * 4);
  float* z    = (float*)alloc((size_t)N_GRAPH * 768 * 4);
  float* z1   = (float*)alloc((size_t)N_GRAPH * 512 * 4);
  float* z2   = (float*)alloc((size_t)N_GRAPH * 256 * 4);

  // zero counters
  hipMemsetAsync(deg, 0, (size_t)(2 * N_NODES + N_GRAPH) * 4, stream);

  // CSR build (by destination) + graph offsets
  k_count_edges<<<(N_EDGES + 255) / 256, 256, 0, stream>>>(e_dst, deg);
  k_count_nodes<<<(N_NODES + 255) / 256, 256, 0, stream>>>(batch, gcnt);
  k_scan<<<1, 1024, 0, stream>>>(deg, rowoff, N_NODES);
  k_scan<<<1, 1024, 0, stream>>>(gcnt, goff, N_GRAPH);
  k_fill<<<(N_EDGES + 255) / 256, 256, 0, stream>>>(e_src, e_dst, rowoff, cursor, csr);
  k_sortseg<<<(N_NODES + 255) / 256, 256, 0, stream>>>(rowoff, csr);

  // ---- layer 1: x[10000,128] @ W1[128,1024] ----
  k_gemm<0><<<dim3(1024 / 64, (N_NODES + 63) / 64), 256, 0, stream>>>(
      x, W1, hA, N_NODES, 128, 1024, nullptr, nullptr);
  k_att<4><<<N_NODES * 4, 64, 0, stream>>>(hA, as1, ad1, aS, aD);
  k_gat_agg<4, 256><<<N_NODES, 256, 0, stream>>>(hA, aS, aD, rowoff, csr, b1, bn1, hB);

  // ---- layer 2: hB[10000,1024] @ W2[1024,1024] ----
  k_gemm<0><<<dim3(1024 / 64, (N_NODES + 63) / 64), 256, 0, stream>>>(
      hB, W2, hA, N_NODES, 1024, 1024, nullptr, nullptr);
  k_att<4><<<N_NODES * 4, 64, 0, stream>>>(hA, as2, ad2, aS, aD);
  k_gat_agg<4, 256><<<N_NODES, 256, 0, stream>>>(hA, aS, aD, rowoff, csr, b2, bn2, hB);

  // ---- layer 3: hB[10000,1024] @ W3[1024,256] ----
  k_gemm<0><<<dim3(256 / 64, (N_NODES + 63) / 64), 256, 0, stream>>>(
      hB, W3, hA, N_NODES, 1024, 256, nullptr, nullptr);
  k_att<1><<<N_NODES, 64, 0, stream>>>(hA, as3, ad3, aS, aD);
  k_gat_agg<1, 256><<<N_NODES, 256, 0, stream>>>(hA, aS, aD, rowoff, csr, b3, bn3, hB);

  // ---- readout + MLP head ----
  k_pool<<<N_GRAPH, 256, 0, stream>>>(hB, goff, z);
  k_gemm<1><<<dim3(512 / 64, 512 / 64), 256, 0, stream>>>(
      z, fc1w, z1, N_GRAPH, 768, 512, fc1b, bnf1);
  k_gemm<1><<<dim3(256 / 64, 512 / 64), 256, 0, stream>>>(
      z1, fc2w, z2, N_GRAPH, 512, 256, fc2b, bnf2);
  k_fc3<<<N_GRAPH, 64, 0, stream>>>(z2, fc3w, fc3b, out);
}

// Round 2
// 503.386 us; speedup vs baseline: 2.0045x; 2.0045x over previous
//
#include <hip/hip_runtime.h>
#include <math.h>

#define N_NODES 10000
#define N_EDGES 160000
#define N_GRAPH 512

#define NEG_INF (-1e30f)

typedef __attribute__((ext_vector_type(8))) short s16x8;
typedef __attribute__((ext_vector_type(4))) float f32x4;

__device__ __forceinline__ unsigned short f2b(float f) {
  union { float f; unsigned u; } c{f};
  unsigned u = c.u;
  return (unsigned short)((u + 0x7fff + ((u >> 16) & 1)) >> 16);
}
__device__ __forceinline__ float b2f(unsigned short h) {
  union { unsigned u; float f; } c{(unsigned)h << 16};
  return c.f;
}

#define GLL16(gp, lp)                                                          \
  __builtin_amdgcn_global_load_lds(                                            \
      (const __attribute__((address_space(1))) unsigned int*)(gp),             \
      (__attribute__((address_space(3))) unsigned int*)(lp), 16, 0, 0)

// ======================= CSR build =======================
__global__ void k_count_edges(const int* __restrict__ dst, int* __restrict__ deg) {
  int e = blockIdx.x * 256 + threadIdx.x;
  if (e < N_EDGES) atomicAdd(&deg[dst[e]], 1);
}

__global__ void k_count_nodes(const int* __restrict__ batch, int* __restrict__ gcnt) {
  int i = blockIdx.x * 256 + threadIdx.x;
  if (i < N_NODES) atomicAdd(&gcnt[batch[i]], 1);
}

__global__ void k_scan(const int* __restrict__ in, int* __restrict__ out, int n) {
  __shared__ int buf[1024];
  __shared__ int carry_s;
  if (threadIdx.x == 0) carry_s = 0;
  __syncthreads();
  for (int base = 0; base < n; base += 1024) {
    int i = base + (int)threadIdx.x;
    int v = (i < n) ? in[i] : 0;
    buf[threadIdx.x] = v;
    __syncthreads();
    for (int off = 1; off < 1024; off <<= 1) {
      int t = (threadIdx.x >= (unsigned)off) ? buf[threadIdx.x - off] : 0;
      __syncthreads();
      buf[threadIdx.x] += t;
      __syncthreads();
    }
    int carry = carry_s;
    if (i < n) out[i] = carry + buf[threadIdx.x] - v;
    __syncthreads();
    if (threadIdx.x == 0) carry_s = carry + buf[1023];
    __syncthreads();
  }
  if (threadIdx.x == 0) out[n] = carry_s;
}

__global__ void k_fill(const int* __restrict__ src, const int* __restrict__ dst,
                       const int* __restrict__ rowoff, int* __restrict__ cursor,
                       int* __restrict__ csr) {
  int e = blockIdx.x * 256 + threadIdx.x;
  if (e < N_EDGES) {
    int d = dst[e];
    int p = atomicAdd(&cursor[d], 1);
    csr[rowoff[d] + p] = src[e];
  }
}

__global__ void k_sortseg(const int* __restrict__ rowoff, int* __restrict__ vals) {
  int i = blockIdx.x * 256 + threadIdx.x;
  if (i >= N_NODES) return;
  int a = rowoff[i], b = rowoff[i + 1];
  for (int p = a + 1; p < b; ++p) {
    int v = vals[p];
    int q = p - 1;
    while (q >= a && vals[q] > v) { vals[q + 1] = vals[q]; --q; }
    vals[q + 1] = v;
  }
}

// ======================= conversions =======================
__global__ void k_f2b4(const float* __restrict__ in, unsigned short* __restrict__ out, int n4) {
  int i = blockIdx.x * 256 + threadIdx.x;
  if (i < n4) {
    float4 v = ((const float4*)in)[i];
    ushort4 o;
    o.x = f2b(v.x); o.y = f2b(v.y); o.z = f2b(v.z); o.w = f2b(v.w);
    ((ushort4*)out)[i] = o;
  }
}

// in [K][M] f32 -> out [M][K] bf16 (transpose + convert). K,M multiples of 32.
__global__ __launch_bounds__(256) void k_convT(const float* __restrict__ in,
                                               unsigned short* __restrict__ out,
                                               int K, int M) {
  __shared__ float t[32][33];
  const int mb = blockIdx.x * 32, kb = blockIdx.y * 32;
  const int tx = threadIdx.x & 31, ty = threadIdx.x >> 5;  // ty 0..7
#pragma unroll
  for (int r = ty; r < 32; r += 8) t[r][tx] = in[(size_t)(kb + r) * M + mb + tx];
  __syncthreads();
#pragma unroll
  for (int r = ty; r < 32; r += 8)
    out[(size_t)(mb + r) * K + kb + tx] = f2b(t[tx][r]);
}

// ======================= bf16 MFMA GEMM =======================
// C[M][N] (bf16) = A[M][K] (bf16) @ Bt[N][K]^T (bf16). 128x128 tile, BK=32.
// 256 threads = 4 waves in 2x2; each wave computes 64x64 via 4x4 16x16 frags.
__global__ __launch_bounds__(256) void k_gemm_bf16(
    const unsigned short* __restrict__ A, const unsigned short* __restrict__ Bt,
    unsigned short* __restrict__ Cbf, int M, int N, int K) {
  __shared__ unsigned short As[128 * 32];
  __shared__ unsigned short Bs[128 * 32];
  const int tid = threadIdx.x;
  const int lane = tid & 63, wave = tid >> 6;
  const int wr = wave >> 1, wc = wave & 1;
  const int m0 = blockIdx.y * 128, n0 = blockIdx.x * 128;

  f32x4 acc[4][4];
#pragma unroll
  for (int i = 0; i < 4; ++i)
#pragma unroll
    for (int j = 0; j < 4; ++j) acc[i][j] = (f32x4){0.f, 0.f, 0.f, 0.f};

  // staging addresses: chunk c = (wave*2+i)*64 + lane; row = c>>2; kpart = c&3
  const int l4 = lane >> 2;
  const int kp8 = (lane & 3) * 8;  // ushort offset within row
  int rA0 = m0 + wave * 32 + l4;
  int rA1 = rA0 + 16;
  rA0 = min(rA0, M - 1);
  rA1 = min(rA1, M - 1);
  const int rB0 = n0 + wave * 32 + l4;
  const int rB1 = rB0 + 16;
  const unsigned short* pA0 = A + (size_t)rA0 * K + kp8;
  const unsigned short* pA1 = A + (size_t)rA1 * K + kp8;
  const unsigned short* pB0 = Bt + (size_t)rB0 * K + kp8;
  const unsigned short* pB1 = Bt + (size_t)rB1 * K + kp8;
  unsigned short* lA = As + wave * 1024;  // wave*2 chunks * 512 ushorts
  unsigned short* lB = Bs + wave * 1024;

  const int fr = lane & 15, kg = (lane >> 4) * 8;

  for (int kb = 0; kb < K; kb += 32) {
    GLL16(pA0 + kb, lA);
    GLL16(pA1 + kb, lA + 512);
    GLL16(pB0 + kb, lB);
    GLL16(pB1 + kb, lB + 512);
    __syncthreads();

    s16x8 a[4], b[4];
#pragma unroll
    for (int m = 0; m < 4; ++m)
      a[m] = *(const s16x8*)&As[(wr * 64 + m * 16 + fr) * 32 + kg];
#pragma unroll
    for (int n = 0; n < 4; ++n)
      b[n] = *(const s16x8*)&Bs[(wc * 64 + n * 16 + fr) * 32 + kg];
#pragma unroll
    for (int m = 0; m < 4; ++m)
#pragma unroll
      for (int n = 0; n < 4; ++n)
        acc[m][n] = __builtin_amdgcn_mfma_f32_16x16x32_bf16(a[m], b[n], acc[m][n], 0, 0, 0);
    __syncthreads();
  }

  const int frow = (lane >> 4) * 4;
#pragma unroll
  for (int m = 0; m < 4; ++m) {
#pragma unroll
    for (int r = 0; r < 4; ++r) {
      const int row = m0 + wr * 64 + m * 16 + frow + r;
      if (row < M) {
#pragma unroll
        for (int n = 0; n < 4; ++n) {
          const int col = n0 + wc * 64 + n * 16 + fr;
          Cbf[(size_t)row * N + col] = f2b(acc[m][n][r]);
        }
      }
    }
  }
}

// ======================= fp32 GEMM (head MLP only) =======================
__global__ __launch_bounds__(256) void k_gemm(
    const float* __restrict__ A, const float* __restrict__ W,
    float* __restrict__ C, int N, int K, int M,
    const float* __restrict__ bias, const float* __restrict__ bn) {
  __shared__ float As[64][17];
  __shared__ float Ws[16][64];
  const int tx = threadIdx.x & 15;
  const int ty = threadIdx.x >> 4;
  const int m0 = blockIdx.y * 64;
  const int n0 = blockIdx.x * 64;
  float acc[4][4];
#pragma unroll
  for (int i = 0; i < 4; ++i)
#pragma unroll
    for (int j = 0; j < 4; ++j) acc[i][j] = 0.f;

  for (int kb = 0; kb < K; kb += 16) {
#pragma unroll
    for (int p = 0; p < 4; ++p) {
      int mr = (int)(threadIdx.x >> 4) + p * 16;
      int kc = threadIdx.x & 15;
      int gm = m0 + mr;
      As[mr][kc] = (gm < N) ? A[(size_t)gm * K + kb + kc] : 0.f;
    }
#pragma unroll
    for (int p = 0; p < 4; ++p) {
      int kr = (int)(threadIdx.x >> 6) + p * 4;
      int nc = threadIdx.x & 63;
      Ws[kr][nc] = W[(size_t)(kb + kr) * M + n0 + nc];
    }
    __syncthreads();
#pragma unroll
    for (int kk = 0; kk < 16; ++kk) {
      float a0 = As[ty * 4 + 0][kk];
      float a1 = As[ty * 4 + 1][kk];
      float a2 = As[ty * 4 + 2][kk];
      float a3 = As[ty * 4 + 3][kk];
      const float4 b4 = *(const float4*)&Ws[kk][tx * 4];
      acc[0][0] += a0 * b4.x; acc[0][1] += a0 * b4.y; acc[0][2] += a0 * b4.z; acc[0][3] += a0 * b4.w;
      acc[1][0] += a1 * b4.x; acc[1][1] += a1 * b4.y; acc[1][2] += a1 * b4.z; acc[1][3] += a1 * b4.w;
      acc[2][0] += a2 * b4.x; acc[2][1] += a2 * b4.y; acc[2][2] += a2 * b4.z; acc[2][3] += a2 * b4.w;
      acc[3][0] += a3 * b4.x; acc[3][1] += a3 * b4.y; acc[3][2] += a3 * b4.z; acc[3][3] += a3 * b4.w;
    }
    __syncthreads();
  }

  const int gn0 = n0 + tx * 4;
#pragma unroll
  for (int i = 0; i < 4; ++i) {
    int gm = m0 + ty * 4 + i;
    if (gm < N) {
      alignas(16) float rr[4];
#pragma unroll
      for (int j = 0; j < 4; ++j) {
        float v = acc[i][j];
        int gn = gn0 + j;
        v += bias[gn];
        float g = bn[gn], b = bn[M + gn], mu = bn[2 * M + gn], var = bn[3 * M + gn];
        v = (v - mu) * (g * rsqrtf(var + 1e-5f)) + b;
        v = v > 0.f ? v : 0.f;
        rr[j] = v;
      }
      *(float4*)&C[(size_t)gm * M + gn0] = *(const float4*)rr;
    }
  }
}

// ======================= attention scores (bf16 h) =======================
template <int HEADS>
__global__ __launch_bounds__(64) void k_att(const unsigned short* __restrict__ h,
                                            const float* __restrict__ att_s,
                                            const float* __restrict__ att_d,
                                            float* __restrict__ aS,
                                            float* __restrict__ aD) {
  const int b = blockIdx.x;  // N_NODES*HEADS
  const int node = b / HEADS, hd = b % HEADS;
  const int lane = threadIdx.x;
  const unsigned short* row = h + (size_t)node * HEADS * 256 + hd * 256;
  const ushort4 v = *(const ushort4*)&row[lane * 4];
  const float4 s4 = *(const float4*)&att_s[hd * 256 + lane * 4];
  const float4 d4 = *(const float4*)&att_d[hd * 256 + lane * 4];
  float ss = b2f(v.x) * s4.x + b2f(v.y) * s4.y + b2f(v.z) * s4.z + b2f(v.w) * s4.w;
  float sd = b2f(v.x) * d4.x + b2f(v.y) * d4.y + b2f(v.z) * d4.z + b2f(v.w) * d4.w;
#pragma unroll
  for (int off = 32; off; off >>= 1) {
    ss += __shfl_xor(ss, off);
    sd += __shfl_xor(sd, off);
  }
  if (lane == 0) {
    aS[node * HEADS + hd] = ss;
    aD[node * HEADS + hd] = sd;
  }
}

// ======================= fused GAT aggregation (bf16 gather) =======================
// OUTBF=1: write bf16 (feeds next GEMM); OUTBF=0: write f32 (feeds pool).
template <int HEADS, int OUTBF>
__global__ __launch_bounds__(256) void k_gat_agg(
    const unsigned short* __restrict__ hpre, const float* __restrict__ aS,
    const float* __restrict__ aD, const int* __restrict__ rowoff,
    const int* __restrict__ csr, const float* __restrict__ bias,
    const float* __restrict__ bn, unsigned short* __restrict__ outb,
    float* __restrict__ outf) {
  constexpr int HC = HEADS * 256;  // 1024 or 256
  constexpr int CPT = HC / 256;    // 4 or 1
  const int node = blockIdx.x;
  const int tid = threadIdx.x;
  const int lane = tid & 63, wave = tid >> 6;
  const int r0 = rowoff[node], r1 = rowoff[node + 1];
  const int deg = r1 - r0;

  __shared__ float s_m[HEADS], s_d[HEADS];
  __shared__ float s_alpha[HEADS * 64];
  __shared__ int s_src[64];

  if (wave < HEADS) {
    const float adn = aD[node * HEADS + wave];
    float mx = NEG_INF;
    for (int i = lane; i < deg; i += 64) {
      int s = csr[r0 + i];
      float l = aS[s * HEADS + wave] + adn;
      l = l > 0.f ? l : 0.2f * l;
      mx = fmaxf(mx, l);
    }
#pragma unroll
    for (int off = 32; off; off >>= 1) mx = fmaxf(mx, __shfl_xor(mx, off));
    float sum = 0.f;
    for (int i = lane; i < deg; i += 64) {
      int s = csr[r0 + i];
      float l = aS[s * HEADS + wave] + adn;
      l = l > 0.f ? l : 0.2f * l;
      sum += __expf(l - mx);
    }
#pragma unroll
    for (int off = 32; off; off >>= 1) sum += __shfl_xor(sum, off);
    if (lane == 0) {
      s_m[wave] = mx;
      s_d[wave] = 1.f / (sum + 1e-16f);
    }
  }
  __syncthreads();

  float acc[CPT];
#pragma unroll
  for (int j = 0; j < CPT; ++j) acc[j] = 0.f;
  const int c0 = tid * CPT;
  const int head = c0 / 256;

  for (int e0 = 0; e0 < deg; e0 += 64) {
    const int cnt = min(64, deg - e0);
    const int eL = tid & 63, hh = tid >> 6;
    if (hh < HEADS && eL < cnt) {
      int s = csr[r0 + e0 + eL];
      if (hh == 0) s_src[eL] = s;
      float l = aS[s * HEADS + hh] + aD[node * HEADS + hh];
      l = l > 0.f ? l : 0.2f * l;
      s_alpha[hh * 64 + eL] = __expf(l - s_m[hh]) * s_d[hh];
    }
    __syncthreads();
    for (int e = 0; e < cnt; ++e) {
      const int s = s_src[e];
      const float al = s_alpha[head * 64 + e];
      if constexpr (CPT == 4) {
        const ushort4 v = *(const ushort4*)(hpre + (size_t)s * HC + c0);
        acc[0] += al * b2f(v.x);
        acc[1] += al * b2f(v.y);
        acc[2] += al * b2f(v.z);
        acc[3] += al * b2f(v.w);
      } else {
        acc[0] += al * b2f(hpre[(size_t)s * HC + c0]);
      }
    }
    __syncthreads();
  }

  // epilogue: +bias, BN(eval), ELU
  if constexpr (CPT == 4) {
    float rr[4];
#pragma unroll
    for (int j = 0; j < 4; ++j) {
      int c = c0 + j;
      float v = acc[j] + bias[c];
      float g = bn[c], b = bn[HC + c], mu = bn[2 * HC + c], var = bn[3 * HC + c];
      v = (v - mu) * (g * rsqrtf(var + 1e-5f)) + b;
      v = v > 0.f ? v : (__expf(v) - 1.f);
      rr[j] = v;
    }
    if (OUTBF) {
      ushort4 o;
      o.x = f2b(rr[0]); o.y = f2b(rr[1]); o.z = f2b(rr[2]); o.w = f2b(rr[3]);
      *(ushort4*)&outb[(size_t)node * HC + c0] = o;
    } else {
      *(float4*)&outf[(size_t)node * HC + c0] = *(const float4*)rr;
    }
  } else {
    int c = c0;
    float v = acc[0] + bias[c];
    float g = bn[c], b = bn[HC + c], mu = bn[2 * HC + c], var = bn[3 * HC + c];
    v = (v - mu) * (g * rsqrtf(var + 1e-5f)) + b;
    v = v > 0.f ? v : (__expf(v) - 1.f);
    if (OUTBF) outb[(size_t)node * HC + c] = f2b(v);
    else outf[(size_t)node * HC + c] = v;
  }
}

// ======================= graph readout =======================
__global__ __launch_bounds__(256) void k_pool(const float* __restrict__ h,
                                              const int* __restrict__ goff,
                                              float* __restrict__ z) {
  const int g = blockIdx.x;
  const int c = threadIdx.x;  // 256
  const int i0 = goff[g], i1 = goff[g + 1];
  float s = 0.f, mx = NEG_INF;
  for (int i = i0; i < i1; ++i) {
    float v = h[(size_t)i * 256 + c];
    s += v;
    mx = fmaxf(mx, v);
  }
  const float cnt = (float)(i1 - i0);
  z[(size_t)g * 768 + c] = s / cnt;
  z[(size_t)g * 768 + 256 + c] = mx;
  z[(size_t)g * 768 + 512 + c] = s;
}

// ======================= fc3 =======================
__global__ __launch_bounds__(64) void k_fc3(const float* __restrict__ z2,
                                            const float* __restrict__ w,
                                            const float* __restrict__ b,
                                            float* __restrict__ out) {
  const int g = blockIdx.x;
  const int lane = threadIdx.x;
  float s = 0.f;
#pragma unroll
  for (int j = 0; j < 4; ++j) {
    int c = lane + 64 * j;
    s += z2[(size_t)g * 256 + c] * w[c];
  }
#pragma unroll
  for (int off = 32; off; off >>= 1) s += __shfl_xor(s, off);
  if (lane == 0) out[g] = s + b[0];
}

// ======================= host launch =======================
extern "C" void kernel_launch(void* const* d_in, const int* in_sizes, int n_in,
                              void* d_out, int out_size, void* d_ws, size_t ws_size,
                              hipStream_t stream) {
  const float* x    = (const float*)d_in[0];
  const int* ei     = (const int*)d_in[1];
  const int* batch  = (const int*)d_in[2];
  const float* W1   = (const float*)d_in[3];
  const float* as1  = (const float*)d_in[4];
  const float* ad1  = (const float*)d_in[5];
  const float* b1   = (const float*)d_in[6];
  const float* bn1  = (const float*)d_in[7];
  const float* W2   = (const float*)d_in[8];
  const float* as2  = (const float*)d_in[9];
  const float* ad2  = (const float*)d_in[10];
  const float* b2   = (const float*)d_in[11];
  const float* bn2  = (const float*)d_in[12];
  const float* W3   = (const float*)d_in[13];
  const float* as3  = (const float*)d_in[14];
  const float* ad3  = (const float*)d_in[15];
  const float* b3   = (const float*)d_in[16];
  const float* bn3  = (const float*)d_in[17];
  const float* fc1w = (const float*)d_in[18];
  const float* fc1b = (const float*)d_in[19];
  const float* bnf1 = (const float*)d_in[20];
  const float* fc2w = (const float*)d_in[21];
  const float* fc2b = (const float*)d_in[22];
  const float* bnf2 = (const float*)d_in[23];
  const float* fc3w = (const float*)d_in[24];
  const float* fc3b = (const float*)d_in[25];
  float* out = (float*)d_out;

  const int* e_src = ei;
  const int* e_dst = ei + N_EDGES;

  char* w = (char*)d_ws;
  auto alloc = [&](size_t bytes) -> void* {
    void* p = (void*)w;
    w += (bytes + 255) & ~(size_t)255;
    return p;
  };
  unsigned short* x_bf  = (unsigned short*)alloc((size_t)N_NODES * 128 * 2);
  unsigned short* W1t   = (unsigned short*)alloc((size_t)1024 * 128 * 2);
  unsigned short* W2t   = (unsigned short*)alloc((size_t)1024 * 1024 * 2);
  unsigned short* W3t   = (unsigned short*)alloc((size_t)256 * 1024 * 2);
  unsigned short* hA_bf = (unsigned short*)alloc((size_t)N_NODES * 1024 * 2);
  unsigned short* hB_bf = (unsigned short*)alloc((size_t)N_NODES * 1024 * 2);
  float* hB_f32 = (float*)alloc((size_t)N_NODES * 256 * 4);
  float* aS   = (float*)alloc((size_t)N_NODES * 4 * 4);
  float* aD   = (float*)alloc((size_t)N_NODES * 4 * 4);
  int* deg    = (int*)alloc((size_t)(2 * N_NODES + N_GRAPH) * 4);
  int* cursor = deg + N_NODES;
  int* gcnt   = deg + 2 * N_NODES;
  int* rowoff = (int*)alloc((size_t)(N_NODES + 1) * 4);
  int* goff   = (int*)alloc((size_t)(N_GRAPH + 1) * 4);
  int* csr    = (int*)alloc((size_t)N_EDGES * 4);
  float* z    = (float*)alloc((size_t)N_GRAPH * 768 * 4);
  float* z1   = (float*)alloc((size_t)N_GRAPH * 512 * 4);
  float* z2   = (float*)alloc((size_t)N_GRAPH * 256 * 4);

  hipMemsetAsync(deg, 0, (size_t)(2 * N_NODES + N_GRAPH) * 4, stream);

  // conversions (independent of CSR build)
  k_f2b4<<<(N_NODES * 128 / 4 + 255) / 256, 256, 0, stream>>>(x, x_bf, N_NODES * 128 / 4);
  k_convT<<<dim3(1024 / 32, 128 / 32), 256, 0, stream>>>(W1, W1t, 128, 1024);
  k_convT<<<dim3(1024 / 32, 1024 / 32), 256, 0, stream>>>(W2, W2t, 1024, 1024);
  k_convT<<<dim3(256 / 32, 1024 / 32), 256, 0, stream>>>(W3, W3t, 1024, 256);

  // CSR build (by destination) + graph offsets
  k_count_edges<<<(N_EDGES + 255) / 256, 256, 0, stream>>>(e_dst, deg);
  k_count_nodes<<<(N_NODES + 255) / 256, 256, 0, stream>>>(batch, gcnt);
  k_scan<<<1, 1024, 0, stream>>>(deg, rowoff, N_NODES);
  k_scan<<<1, 1024, 0, stream>>>(gcnt, goff, N_GRAPH);
  k_fill<<<(N_EDGES + 255) / 256, 256, 0, stream>>>(e_src, e_dst, rowoff, cursor, csr);
  k_sortseg<<<(N_NODES + 255) / 256, 256, 0, stream>>>(rowoff, csr);

  const int mt = (N_NODES + 127) / 128;  // 79

  // ---- layer 1 ----
  k_gemm_bf16<<<dim3(1024 / 128, mt), 256, 0, stream>>>(x_bf, W1t, hA_bf, N_NODES, 1024, 128);
  k_att<4><<<N_NODES * 4, 64, 0, stream>>>(hA_bf, as1, ad1, aS, aD);
  k_gat_agg<4, 1><<<N_NODES, 256, 0, stream>>>(hA_bf, aS, aD, rowoff, csr, b1, bn1, hB_bf, nullptr);

  // ---- layer 2 ----
  k_gemm_bf16<<<dim3(1024 / 128, mt), 256, 0, stream>>>(hB_bf, W2t, hA_bf, N_NODES, 1024, 1024);
  k_att<4><<<N_NODES * 4, 64, 0, stream>>>(hA_bf, as2, ad2, aS, aD);
  k_gat_agg<4, 1><<<N_NODES, 256, 0, stream>>>(hA_bf, aS, aD, rowoff, csr, b2, bn2, hB_bf, nullptr);

  // ---- layer 3 ----
  k_gemm_bf16<<<dim3(256 / 128, mt), 256, 0, stream>>>(hB_bf, W3t, hA_bf, N_NODES, 256, 1024);
  k_att<1><<<N_NODES, 64, 0, stream>>>(hA_bf, as3, ad3, aS, aD);
  k_gat_agg<1, 0><<<N_NODES, 256, 0, stream>>>(hA_bf, aS, aD, rowoff, csr, b3, bn3, nullptr, hB_f32);

  // ---- readout + MLP head ----
  k_pool<<<N_GRAPH, 256, 0, stream>>>(hB_f32, goff, z);
  k_gemm<<<dim3(512 / 64, 512 / 64), 256, 0, stream>>>(z, fc1w, z1, N_GRAPH, 768, 512, fc1b, bnf1);
  k_gemm<<<dim3(256 / 64, 512 / 64), 256, 0, stream>>>(z1, fc2w, z2, N_GRAPH, 512, 256, fc2b, bnf2);
  k_fc3<<<N_GRAPH, 64, 0, stream>>>(z2, fc3w, fc3b, out);
}

// Round 3
// 405.390 us; speedup vs baseline: 2.4890x; 1.2417x over previous
//
#include <hip/hip_runtime.h>
#include <math.h>

#define N_NODES 10000
#define N_EDGES 160000
#define N_GRAPH 512

#define NEG_INF (-1e30f)

typedef __attribute__((ext_vector_type(8))) short s16x8;
typedef __attribute__((ext_vector_type(4))) float f32x4;

__device__ __forceinline__ unsigned short f2b(float f) {
  union { float f; unsigned u; } c{f};
  unsigned u = c.u;
  return (unsigned short)((u + 0x7fff + ((u >> 16) & 1)) >> 16);
}
__device__ __forceinline__ float b2f(unsigned short h) {
  union { unsigned u; float f; } c{(unsigned)h << 16};
  return c.f;
}

#define GLL16(gp, lp)                                                          \
  __builtin_amdgcn_global_load_lds(                                            \
      (const __attribute__((address_space(1))) unsigned int*)(gp),             \
      (__attribute__((address_space(3))) unsigned int*)(lp), 16, 0, 0)

// ======================= CSR build =======================
__global__ void k_count_edges(const int* __restrict__ dst, int* __restrict__ deg) {
  int e = blockIdx.x * 256 + threadIdx.x;
  if (e < N_EDGES) atomicAdd(&deg[dst[e]], 1);
}

__global__ void k_count_nodes(const int* __restrict__ batch, int* __restrict__ gcnt) {
  int i = blockIdx.x * 256 + threadIdx.x;
  if (i < N_NODES) atomicAdd(&gcnt[batch[i]], 1);
}

__global__ void k_scan(const int* __restrict__ in, int* __restrict__ out, int n) {
  __shared__ int buf[1024];
  __shared__ int carry_s;
  if (threadIdx.x == 0) carry_s = 0;
  __syncthreads();
  for (int base = 0; base < n; base += 1024) {
    int i = base + (int)threadIdx.x;
    int v = (i < n) ? in[i] : 0;
    buf[threadIdx.x] = v;
    __syncthreads();
    for (int off = 1; off < 1024; off <<= 1) {
      int t = (threadIdx.x >= (unsigned)off) ? buf[threadIdx.x - off] : 0;
      __syncthreads();
      buf[threadIdx.x] += t;
      __syncthreads();
    }
    int carry = carry_s;
    if (i < n) out[i] = carry + buf[threadIdx.x] - v;
    __syncthreads();
    if (threadIdx.x == 0) carry_s = carry + buf[1023];
    __syncthreads();
  }
  if (threadIdx.x == 0) out[n] = carry_s;
}

__global__ void k_fill(const int* __restrict__ src, const int* __restrict__ dst,
                       const int* __restrict__ rowoff, int* __restrict__ cursor,
                       int* __restrict__ csr) {
  int e = blockIdx.x * 256 + threadIdx.x;
  if (e < N_EDGES) {
    int d = dst[e];
    int p = atomicAdd(&cursor[d], 1);
    csr[rowoff[d] + p] = src[e];
  }
}

// wave-per-node odd-even transposition sort (deterministic CSR order)
__global__ __launch_bounds__(256) void k_sortseg(const int* __restrict__ rowoff,
                                                 int* __restrict__ vals) {
  const int node = blockIdx.x * 4 + (threadIdx.x >> 6);
  if (node >= N_NODES) return;
  const int lane = threadIdx.x & 63;
  const int a = rowoff[node], b = rowoff[node + 1];
  const int deg = b - a;
  if (deg <= 1) return;
  if (deg <= 64) {
    int v = (lane < deg) ? vals[a + lane] : 0x7fffffff;
#pragma unroll
    for (int ph = 0; ph < 64; ++ph) {
      const int par = ph & 1;
      const bool left = ((lane & 1) == par);
      const int partner = left ? lane + 1 : lane - 1;
      const int pv = __shfl(v, partner & 63);
      if (partner >= 0 && partner < 64) v = left ? min(v, pv) : max(v, pv);
    }
    if (lane < deg) vals[a + lane] = v;
  } else if (lane == 0) {
    for (int p = a + 1; p < b; ++p) {
      int v = vals[p];
      int q = p - 1;
      while (q >= a && vals[q] > v) { vals[q + 1] = vals[q]; --q; }
      vals[q + 1] = v;
    }
  }
}

// ======================= conversions =======================
__global__ void k_f2b4(const float* __restrict__ in, unsigned short* __restrict__ out, int n4) {
  int i = blockIdx.x * 256 + threadIdx.x;
  if (i < n4) {
    float4 v = ((const float4*)in)[i];
    ushort4 o;
    o.x = f2b(v.x); o.y = f2b(v.y); o.z = f2b(v.z); o.w = f2b(v.w);
    ((ushort4*)out)[i] = o;
  }
}

// in [K][M] f32 -> out [M][K] bf16 (transpose + convert). K,M multiples of 32.
__global__ __launch_bounds__(256) void k_convT(const float* __restrict__ in,
                                               unsigned short* __restrict__ out,
                                               int K, int M) {
  __shared__ float t[32][33];
  const int mb = blockIdx.x * 32, kb = blockIdx.y * 32;
  const int tx = threadIdx.x & 31, ty = threadIdx.x >> 5;
#pragma unroll
  for (int r = ty; r < 32; r += 8) t[r][tx] = in[(size_t)(kb + r) * M + mb + tx];
  __syncthreads();
#pragma unroll
  for (int r = ty; r < 32; r += 8)
    out[(size_t)(mb + r) * K + kb + tx] = f2b(t[tx][r]);
}

// ======================= bf16 MFMA GEMM =======================
// C[M][N] (bf16) = A[M][K] (bf16) @ Bt[N][K]^T (bf16). 128x128 tile, BK=32.
__global__ __launch_bounds__(256) void k_gemm_bf16(
    const unsigned short* __restrict__ A, const unsigned short* __restrict__ Bt,
    unsigned short* __restrict__ Cbf, int M, int N, int K) {
  __shared__ unsigned short As[128 * 32];
  __shared__ unsigned short Bs[128 * 32];
  const int tid = threadIdx.x;
  const int lane = tid & 63, wave = tid >> 6;
  const int wr = wave >> 1, wc = wave & 1;
  const int m0 = blockIdx.y * 128, n0 = blockIdx.x * 128;

  f32x4 acc[4][4];
#pragma unroll
  for (int i = 0; i < 4; ++i)
#pragma unroll
    for (int j = 0; j < 4; ++j) acc[i][j] = (f32x4){0.f, 0.f, 0.f, 0.f};

  const int l4 = lane >> 2;
  const int kp8 = (lane & 3) * 8;
  int rA0 = m0 + wave * 32 + l4;
  int rA1 = rA0 + 16;
  rA0 = min(rA0, M - 1);
  rA1 = min(rA1, M - 1);
  const int rB0 = n0 + wave * 32 + l4;
  const int rB1 = rB0 + 16;
  const unsigned short* pA0 = A + (size_t)rA0 * K + kp8;
  const unsigned short* pA1 = A + (size_t)rA1 * K + kp8;
  const unsigned short* pB0 = Bt + (size_t)rB0 * K + kp8;
  const unsigned short* pB1 = Bt + (size_t)rB1 * K + kp8;
  unsigned short* lA = As + wave * 1024;
  unsigned short* lB = Bs + wave * 1024;

  const int fr = lane & 15, kg = (lane >> 4) * 8;

  for (int kb = 0; kb < K; kb += 32) {
    GLL16(pA0 + kb, lA);
    GLL16(pA1 + kb, lA + 512);
    GLL16(pB0 + kb, lB);
    GLL16(pB1 + kb, lB + 512);
    __syncthreads();

    s16x8 a[4], b[4];
#pragma unroll
    for (int m = 0; m < 4; ++m)
      a[m] = *(const s16x8*)&As[(wr * 64 + m * 16 + fr) * 32 + kg];
#pragma unroll
    for (int n = 0; n < 4; ++n)
      b[n] = *(const s16x8*)&Bs[(wc * 64 + n * 16 + fr) * 32 + kg];
#pragma unroll
    for (int m = 0; m < 4; ++m)
#pragma unroll
      for (int n = 0; n < 4; ++n)
        acc[m][n] = __builtin_amdgcn_mfma_f32_16x16x32_bf16(a[m], b[n], acc[m][n], 0, 0, 0);
    __syncthreads();
  }

  const int frow = (lane >> 4) * 4;
#pragma unroll
  for (int m = 0; m < 4; ++m) {
#pragma unroll
    for (int r = 0; r < 4; ++r) {
      const int row = m0 + wr * 64 + m * 16 + frow + r;
      if (row < M) {
#pragma unroll
        for (int n = 0; n < 4; ++n) {
          const int col = n0 + wc * 64 + n * 16 + fr;
          Cbf[(size_t)row * N + col] = f2b(acc[m][n][r]);
        }
      }
    }
  }
}

// ======================= fp32 GEMM, 32x32 tiles (head MLP) =======================
// C[N][M] = relu(bn(A[N][K] @ W[K][M] + bias)). 256 thr, 2x2 per thread.
__global__ __launch_bounds__(256) void k_gemm_s(
    const float* __restrict__ A, const float* __restrict__ W,
    float* __restrict__ C, int N, int K, int M,
    const float* __restrict__ bias, const float* __restrict__ bn) {
  __shared__ float As[32][17];
  __shared__ float Ws[16][33];
  const int tx = threadIdx.x & 15;   // col group
  const int ty = threadIdx.x >> 4;   // row group
  const int n0 = blockIdx.y * 32;    // rows (graphs)
  const int m0 = blockIdx.x * 32;    // cols
  float acc[2][2] = {{0.f, 0.f}, {0.f, 0.f}};

  for (int kb = 0; kb < K; kb += 16) {
    // A tile 32x16: thread loads rows ty, ty+16 at col tx
    {
      int r0 = n0 + ty, r1 = n0 + ty + 16;
      As[ty][tx] = (r0 < N) ? A[(size_t)r0 * K + kb + tx] : 0.f;
      As[ty + 16][tx] = (r1 < N) ? A[(size_t)r1 * K + kb + tx] : 0.f;
    }
    // W tile 16x32: row ty, cols tx, tx+16
    Ws[ty][tx] = W[(size_t)(kb + ty) * M + m0 + tx];
    Ws[ty][tx + 16] = W[(size_t)(kb + ty) * M + m0 + tx + 16];
    __syncthreads();
#pragma unroll
    for (int kk = 0; kk < 16; ++kk) {
      float a0 = As[ty * 2][kk], a1 = As[ty * 2 + 1][kk];
      float b0 = Ws[kk][tx * 2], b1 = Ws[kk][tx * 2 + 1];
      acc[0][0] += a0 * b0; acc[0][1] += a0 * b1;
      acc[1][0] += a1 * b0; acc[1][1] += a1 * b1;
    }
    __syncthreads();
  }

#pragma unroll
  for (int i = 0; i < 2; ++i) {
    int gr = n0 + ty * 2 + i;
    if (gr < N) {
#pragma unroll
      for (int j = 0; j < 2; ++j) {
        int gc = m0 + tx * 2 + j;
        float v = acc[i][j] + bias[gc];
        float g = bn[gc], b = bn[M + gc], mu = bn[2 * M + gc], var = bn[3 * M + gc];
        v = (v - mu) * (g * rsqrtf(var + 1e-5f)) + b;
        v = v > 0.f ? v : 0.f;
        C[(size_t)gr * M + gc] = v;
      }
    }
  }
}

// ======================= attention scores (bf16 h) =======================
template <int HEADS>
__global__ __launch_bounds__(64) void k_att(const unsigned short* __restrict__ h,
                                            const float* __restrict__ att_s,
                                            const float* __restrict__ att_d,
                                            float* __restrict__ aS,
                                            float* __restrict__ aD) {
  const int b = blockIdx.x;
  const int node = b / HEADS, hd = b % HEADS;
  const int lane = threadIdx.x;
  const unsigned short* row = h + (size_t)node * HEADS * 256 + hd * 256;
  const ushort4 v = *(const ushort4*)&row[lane * 4];
  const float4 s4 = *(const float4*)&att_s[hd * 256 + lane * 4];
  const float4 d4 = *(const float4*)&att_d[hd * 256 + lane * 4];
  float ss = b2f(v.x) * s4.x + b2f(v.y) * s4.y + b2f(v.z) * s4.z + b2f(v.w) * s4.w;
  float sd = b2f(v.x) * d4.x + b2f(v.y) * d4.y + b2f(v.z) * d4.z + b2f(v.w) * d4.w;
#pragma unroll
  for (int off = 32; off; off >>= 1) {
    ss += __shfl_xor(ss, off);
    sd += __shfl_xor(sd, off);
  }
  if (lane == 0) {
    aS[node * HEADS + hd] = ss;
    aD[node * HEADS + hd] = sd;
  }
}

// ======================= fused GAT aggregation (bf16 gather) =======================
template <int HEADS, int OUTBF>
__global__ __launch_bounds__(256) void k_gat_agg(
    const unsigned short* __restrict__ hpre, const float* __restrict__ aS,
    const float* __restrict__ aD, const int* __restrict__ rowoff,
    const int* __restrict__ csr, const float* __restrict__ bias,
    const float* __restrict__ bn, unsigned short* __restrict__ outb,
    float* __restrict__ outf) {
  constexpr int HC = HEADS * 256;
  constexpr int CPT = HC / 256;
  const int node = blockIdx.x;
  const int tid = threadIdx.x;
  const int lane = tid & 63, wave = tid >> 6;
  const int r0 = rowoff[node], r1 = rowoff[node + 1];
  const int deg = r1 - r0;

  __shared__ float s_m[HEADS], s_d[HEADS];
  __shared__ float s_alpha[HEADS * 64];
  __shared__ int s_src[64];

  if (wave < HEADS) {
    const float adn = aD[node * HEADS + wave];
    float mx = NEG_INF;
    for (int i = lane; i < deg; i += 64) {
      int s = csr[r0 + i];
      float l = aS[s * HEADS + wave] + adn;
      l = l > 0.f ? l : 0.2f * l;
      mx = fmaxf(mx, l);
    }
#pragma unroll
    for (int off = 32; off; off >>= 1) mx = fmaxf(mx, __shfl_xor(mx, off));
    float sum = 0.f;
    for (int i = lane; i < deg; i += 64) {
      int s = csr[r0 + i];
      float l = aS[s * HEADS + wave] + adn;
      l = l > 0.f ? l : 0.2f * l;
      sum += __expf(l - mx);
    }
#pragma unroll
    for (int off = 32; off; off >>= 1) sum += __shfl_xor(sum, off);
    if (lane == 0) {
      s_m[wave] = mx;
      s_d[wave] = 1.f / (sum + 1e-16f);
    }
  }
  __syncthreads();

  float acc[CPT];
#pragma unroll
  for (int j = 0; j < CPT; ++j) acc[j] = 0.f;
  const int c0 = tid * CPT;
  const int head = c0 / 256;

  for (int e0 = 0; e0 < deg; e0 += 64) {
    const int cnt = min(64, deg - e0);
    const int eL = tid & 63, hh = tid >> 6;
    if (hh < HEADS && eL < cnt) {
      int s = csr[r0 + e0 + eL];
      if (hh == 0) s_src[eL] = s;
      float l = aS[s * HEADS + hh] + aD[node * HEADS + hh];
      l = l > 0.f ? l : 0.2f * l;
      s_alpha[hh * 64 + eL] = __expf(l - s_m[hh]) * s_d[hh];
    }
    __syncthreads();
    for (int e = 0; e < cnt; ++e) {
      const int s = s_src[e];
      const float al = s_alpha[head * 64 + e];
      if constexpr (CPT == 4) {
        const ushort4 v = *(const ushort4*)(hpre + (size_t)s * HC + c0);
        acc[0] += al * b2f(v.x);
        acc[1] += al * b2f(v.y);
        acc[2] += al * b2f(v.z);
        acc[3] += al * b2f(v.w);
      } else {
        acc[0] += al * b2f(hpre[(size_t)s * HC + c0]);
      }
    }
    __syncthreads();
  }

  if constexpr (CPT == 4) {
    float rr[4];
#pragma unroll
    for (int j = 0; j < 4; ++j) {
      int c = c0 + j;
      float v = acc[j] + bias[c];
      float g = bn[c], b = bn[HC + c], mu = bn[2 * HC + c], var = bn[3 * HC + c];
      v = (v - mu) * (g * rsqrtf(var + 1e-5f)) + b;
      v = v > 0.f ? v : (__expf(v) - 1.f);
      rr[j] = v;
    }
    if (OUTBF) {
      ushort4 o;
      o.x = f2b(rr[0]); o.y = f2b(rr[1]); o.z = f2b(rr[2]); o.w = f2b(rr[3]);
      *(ushort4*)&outb[(size_t)node * HC + c0] = o;
    } else {
      *(float4*)&outf[(size_t)node * HC + c0] = *(const float4*)rr;
    }
  } else {
    int c = c0;
    float v = acc[0] + bias[c];
    float g = bn[c], b = bn[HC + c], mu = bn[2 * HC + c], var = bn[3 * HC + c];
    v = (v - mu) * (g * rsqrtf(var + 1e-5f)) + b;
    v = v > 0.f ? v : (__expf(v) - 1.f);
    if (OUTBF) outb[(size_t)node * HC + c] = f2b(v);
    else outf[(size_t)node * HC + c] = v;
  }
}

// ======================= graph readout =======================
__global__ __launch_bounds__(256) void k_pool(const float* __restrict__ h,
                                              const int* __restrict__ goff,
                                              float* __restrict__ z) {
  const int g = blockIdx.x;
  const int c = threadIdx.x;
  const int i0 = goff[g], i1 = goff[g + 1];
  float s = 0.f, mx = NEG_INF;
  for (int i = i0; i < i1; ++i) {
    float v = h[(size_t)i * 256 + c];
    s += v;
    mx = fmaxf(mx, v);
  }
  const float cnt = (float)(i1 - i0);
  z[(size_t)g * 768 + c] = s / cnt;
  z[(size_t)g * 768 + 256 + c] = mx;
  z[(size_t)g * 768 + 512 + c] = s;
}

// ======================= fc3 =======================
__global__ __launch_bounds__(64) void k_fc3(const float* __restrict__ z2,
                                            const float* __restrict__ w,
                                            const float* __restrict__ b,
                                            float* __restrict__ out) {
  const int g = blockIdx.x;
  const int lane = threadIdx.x;
  float s = 0.f;
#pragma unroll
  for (int j = 0; j < 4; ++j) {
    int c = lane + 64 * j;
    s += z2[(size_t)g * 256 + c] * w[c];
  }
#pragma unroll
  for (int off = 32; off; off >>= 1) s += __shfl_xor(s, off);
  if (lane == 0) out[g] = s + b[0];
}

// ======================= host launch =======================
extern "C" void kernel_launch(void* const* d_in, const int* in_sizes, int n_in,
                              void* d_out, int out_size, void* d_ws, size_t ws_size,
                              hipStream_t stream) {
  const float* x    = (const float*)d_in[0];
  const int* ei     = (const int*)d_in[1];
  const int* batch  = (const int*)d_in[2];
  const float* W1   = (const float*)d_in[3];
  const float* as1  = (const float*)d_in[4];
  const float* ad1  = (const float*)d_in[5];
  const float* b1   = (const float*)d_in[6];
  const float* bn1  = (const float*)d_in[7];
  const float* W2   = (const float*)d_in[8];
  const float* as2  = (const float*)d_in[9];
  const float* ad2  = (const float*)d_in[10];
  const float* b2   = (const float*)d_in[11];
  const float* bn2  = (const float*)d_in[12];
  const float* W3   = (const float*)d_in[13];
  const float* as3  = (const float*)d_in[14];
  const float* ad3  = (const float*)d_in[15];
  const float* b3   = (const float*)d_in[16];
  const float* bn3  = (const float*)d_in[17];
  const float* fc1w = (const float*)d_in[18];
  const float* fc1b = (const float*)d_in[19];
  const float* bnf1 = (const float*)d_in[20];
  const float* fc2w = (const float*)d_in[21];
  const float* fc2b = (const float*)d_in[22];
  const float* bnf2 = (const float*)d_in[23];
  const float* fc3w = (const float*)d_in[24];
  const float* fc3b = (const float*)d_in[25];
  float* out = (float*)d_out;

  const int* e_src = ei;
  const int* e_dst = ei + N_EDGES;

  char* w = (char*)d_ws;
  auto alloc = [&](size_t bytes) -> void* {
    void* p = (void*)w;
    w += (bytes + 255) & ~(size_t)255;
    return p;
  };
  unsigned short* x_bf  = (unsigned short*)alloc((size_t)N_NODES * 128 * 2);
  unsigned short* W1t   = (unsigned short*)alloc((size_t)1024 * 128 * 2);
  unsigned short* W2t   = (unsigned short*)alloc((size_t)1024 * 1024 * 2);
  unsigned short* W3t   = (unsigned short*)alloc((size_t)256 * 1024 * 2);
  unsigned short* hA_bf = (unsigned short*)alloc((size_t)N_NODES * 1024 * 2);
  unsigned short* hB_bf = (unsigned short*)alloc((size_t)N_NODES * 1024 * 2);
  float* hB_f32 = (float*)alloc((size_t)N_NODES * 256 * 4);
  float* aS   = (float*)alloc((size_t)N_NODES * 4 * 4);
  float* aD   = (float*)alloc((size_t)N_NODES * 4 * 4);
  int* deg    = (int*)alloc((size_t)(2 * N_NODES + N_GRAPH) * 4);
  int* cursor = deg + N_NODES;
  int* gcnt   = deg + 2 * N_NODES;
  int* rowoff = (int*)alloc((size_t)(N_NODES + 1) * 4);
  int* goff   = (int*)alloc((size_t)(N_GRAPH + 1) * 4);
  int* csr    = (int*)alloc((size_t)N_EDGES * 4);
  float* z    = (float*)alloc((size_t)N_GRAPH * 768 * 4);
  float* z1   = (float*)alloc((size_t)N_GRAPH * 512 * 4);
  float* z2   = (float*)alloc((size_t)N_GRAPH * 256 * 4);

  hipMemsetAsync(deg, 0, (size_t)(2 * N_NODES + N_GRAPH) * 4, stream);

  // conversions (independent of CSR build)
  k_f2b4<<<(N_NODES * 128 / 4 + 255) / 256, 256, 0, stream>>>(x, x_bf, N_NODES * 128 / 4);
  k_convT<<<dim3(1024 / 32, 128 / 32), 256, 0, stream>>>(W1, W1t, 128, 1024);
  k_convT<<<dim3(1024 / 32, 1024 / 32), 256, 0, stream>>>(W2, W2t, 1024, 1024);
  k_convT<<<dim3(256 / 32, 1024 / 32), 256, 0, stream>>>(W3, W3t, 1024, 256);

  // CSR build (by destination) + graph offsets
  k_count_edges<<<(N_EDGES + 255) / 256, 256, 0, stream>>>(e_dst, deg);
  k_count_nodes<<<(N_NODES + 255) / 256, 256, 0, stream>>>(batch, gcnt);
  k_scan<<<1, 1024, 0, stream>>>(deg, rowoff, N_NODES);
  k_scan<<<1, 1024, 0, stream>>>(gcnt, goff, N_GRAPH);
  k_fill<<<(N_EDGES + 255) / 256, 256, 0, stream>>>(e_src, e_dst, rowoff, cursor, csr);
  k_sortseg<<<(N_NODES + 3) / 4, 256, 0, stream>>>(rowoff, csr);

  const int mt = (N_NODES + 127) / 128;  // 79

  // ---- layer 1 ----
  k_gemm_bf16<<<dim3(1024 / 128, mt), 256, 0, stream>>>(x_bf, W1t, hA_bf, N_NODES, 1024, 128);
  k_att<4><<<N_NODES * 4, 64, 0, stream>>>(hA_bf, as1, ad1, aS, aD);
  k_gat_agg<4, 1><<<N_NODES, 256, 0, stream>>>(hA_bf, aS, aD, rowoff, csr, b1, bn1, hB_bf, nullptr);

  // ---- layer 2 ----
  k_gemm_bf16<<<dim3(1024 / 128, mt), 256, 0, stream>>>(hB_bf, W2t, hA_bf, N_NODES, 1024, 1024);
  k_att<4><<<N_NODES * 4, 64, 0, stream>>>(hA_bf, as2, ad2, aS, aD);
  k_gat_agg<4, 1><<<N_NODES, 256, 0, stream>>>(hA_bf, aS, aD, rowoff, csr, b2, bn2, hB_bf, nullptr);

  // ---- layer 3 ----
  k_gemm_bf16<<<dim3(256 / 128, mt), 256, 0, stream>>>(hB_bf, W3t, hA_bf, N_NODES, 256, 1024);
  k_att<1><<<N_NODES, 64, 0, stream>>>(hA_bf, as3, ad3, aS, aD);
  k_gat_agg<1, 0><<<N_NODES, 256, 0, stream>>>(hA_bf, aS, aD, rowoff, csr, b3, bn3, nullptr, hB_f32);

  // ---- readout + MLP head ----
  k_pool<<<N_GRAPH, 256, 0, stream>>>(hB_f32, goff, z);
  k_gemm_s<<<dim3(512 / 32, 512 / 32), 256, 0, stream>>>(z, fc1w, z1, N_GRAPH, 768, 512, fc1b, bnf1);
  k_gemm_s<<<dim3(256 / 32, 512 / 32), 256, 0, stream>>>(z1, fc2w, z2, N_GRAPH, 512, 256, fc2b, bnf2);
  k_fc3<<<N_GRAPH, 64, 0, stream>>>(z2, fc3w, fc3b, out);
}